// Round 1
// baseline (6389.655 us; speedup 1.0000x reference)
//
#include <hip/hip_runtime.h>
#include <cmath>

#define BATCH 64
#define SEQ   512
#define ISZ   512
#define HSZ   1024
// M = BATCH*SEQ = 32768

// ---------------------------------------------------------------------------
// Kernel 1: x_proj = inputs @ W_xh + b_h   (fp32 tiled GEMM, written to d_out)
// M=32768, K=512, N=1024. Tile 64x64, BK=32, 256 threads, 4x4 micro-tile.
// ---------------------------------------------------------------------------
__global__ __launch_bounds__(256) void xproj_gemm(
    const float* __restrict__ A,     // (32768, 512)
    const float* __restrict__ Bw,    // (512, 1024)
    const float* __restrict__ bias,  // (1024,)
    float* __restrict__ C) {         // (32768, 1024)
  __shared__ float As[32 * 68];      // [k][m], pad 68 keeps float4 alignment
  __shared__ float Bs[32 * 64];      // [k][n]

  const int tid = threadIdx.x;
  const int n0 = blockIdx.x * 64;
  const int m0 = blockIdx.y * 64;
  const int ty = tid >> 4;           // 0..15 -> rows ty*4..ty*4+3
  const int tx = tid & 15;           // 0..15 -> cols tx*4..tx*4+3

  float acc[4][4] = {};

  for (int kt = 0; kt < ISZ; kt += 32) {
    // Load A tile 64x32 (global coalesced over k, LDS transposed store)
#pragma unroll
    for (int i = 0; i < 8; ++i) {
      int idx = tid + i * 256;       // 0..2047
      int m = idx >> 5, k = idx & 31;
      As[k * 68 + m] = A[(size_t)(m0 + m) * ISZ + kt + k];
    }
    // Load B tile 32x64 (global coalesced over n)
#pragma unroll
    for (int i = 0; i < 8; ++i) {
      int idx = tid + i * 256;       // 0..2047
      int k = idx >> 6, n = idx & 63;
      Bs[k * 64 + n] = Bw[(size_t)(kt + k) * HSZ + n0 + n];
    }
    __syncthreads();

#pragma unroll
    for (int k = 0; k < 32; ++k) {
      const float4 a4 = *(const float4*)(&As[k * 68 + ty * 4]);
      const float4 b4 = *(const float4*)(&Bs[k * 64 + tx * 4]);
      acc[0][0] = fmaf(a4.x, b4.x, acc[0][0]);
      acc[0][1] = fmaf(a4.x, b4.y, acc[0][1]);
      acc[0][2] = fmaf(a4.x, b4.z, acc[0][2]);
      acc[0][3] = fmaf(a4.x, b4.w, acc[0][3]);
      acc[1][0] = fmaf(a4.y, b4.x, acc[1][0]);
      acc[1][1] = fmaf(a4.y, b4.y, acc[1][1]);
      acc[1][2] = fmaf(a4.y, b4.z, acc[1][2]);
      acc[1][3] = fmaf(a4.y, b4.w, acc[1][3]);
      acc[2][0] = fmaf(a4.z, b4.x, acc[2][0]);
      acc[2][1] = fmaf(a4.z, b4.y, acc[2][1]);
      acc[2][2] = fmaf(a4.z, b4.z, acc[2][2]);
      acc[2][3] = fmaf(a4.z, b4.w, acc[2][3]);
      acc[3][0] = fmaf(a4.w, b4.x, acc[3][0]);
      acc[3][1] = fmaf(a4.w, b4.y, acc[3][1]);
      acc[3][2] = fmaf(a4.w, b4.z, acc[3][2]);
      acc[3][3] = fmaf(a4.w, b4.w, acc[3][3]);
    }
    __syncthreads();
  }

  const float4 bv = *(const float4*)(&bias[n0 + tx * 4]);
#pragma unroll
  for (int r = 0; r < 4; ++r) {
    float4 o;
    o.x = acc[r][0] + bv.x;
    o.y = acc[r][1] + bv.y;
    o.z = acc[r][2] + bv.z;
    o.w = acc[r][3] + bv.w;
    *(float4*)(&C[(size_t)(m0 + ty * 4 + r) * HSZ + n0 + tx * 4]) = o;
  }
}

// ---------------------------------------------------------------------------
// Kernel 2: copy h_prev into workspace h buffer
// ---------------------------------------------------------------------------
__global__ void copy_h(const float* __restrict__ src, float* __restrict__ dst) {
  int idx = blockIdx.x * 256 + threadIdx.x;  // grid 256x256 = 65536
  dst[idx] = src[idx];
}

// ---------------------------------------------------------------------------
// Kernel 3: one RNN timestep.
//   h_next = tanh(xp_t + h @ W_hh), xp_t read in-place from d_out[:, t, :],
//   h_next written both to d_out[:, t, :] and the next h buffer.
// Grid: (32 n-tiles, 8 b-tiles). WG tile = 8 batches x 32 cols, 256 threads.
// 4 waves split K=1024 into 256-chunks; LDS partial reduction at the end.
// ---------------------------------------------------------------------------
__global__ __launch_bounds__(256) void rnn_step(
    const float* __restrict__ h,    // (64, 1024) current hidden
    const float* __restrict__ W,    // (1024, 1024) W_hh
    float* __restrict__ out,        // (64, 512, 1024)
    float* __restrict__ hn,         // (64, 1024) next hidden
    int t) {
  __shared__ float Hs[8 * 1028];    // pad +4: 8 same-k readers hit 8 banks
  __shared__ float Ps[4 * 8 * 32];  // per-wave partials [wave][b][n]

  const int tid = threadIdx.x;
  const int n0 = blockIdx.x * 32;
  const int b0 = blockIdx.y * 8;

  // Stage H tile (8 rows x 1024), coalesced
  for (int idx = tid; idx < 8 * 1024; idx += 256) {
    int r = idx >> 10, c = idx & 1023;
    Hs[r * 1028 + c] = h[(size_t)(b0 + r) * HSZ + c];
  }
  __syncthreads();

  const int wave = tid >> 6;        // 0..3 -> K chunk
  const int lane = tid & 63;
  const int b = lane >> 3;          // 0..7
  const int q = lane & 7;           // 0..7 -> cols n0 + q*4 .. +3
  const int k0 = wave * 256;

  const float* Wp = W + (size_t)k0 * HSZ + n0 + q * 4;
  const float* Hp = &Hs[b * 1028 + k0];

  float4 acc = make_float4(0.f, 0.f, 0.f, 0.f);
#pragma unroll 8
  for (int k = 0; k < 256; ++k) {
    const float hv = Hp[k];
    const float4 w4 = *(const float4*)(Wp + (size_t)k * HSZ);
    acc.x = fmaf(hv, w4.x, acc.x);
    acc.y = fmaf(hv, w4.y, acc.y);
    acc.z = fmaf(hv, w4.z, acc.z);
    acc.w = fmaf(hv, w4.w, acc.w);
  }
  *(float4*)(&Ps[(wave * 8 + b) * 32 + q * 4]) = acc;
  __syncthreads();

  // Reduce 4 wave partials; 256 threads cover the 8x32 tile
  const int ty = tid >> 5;          // 0..7  batch row
  const int tx = tid & 31;          // 0..31 col
  float s = Ps[(0 * 8 + ty) * 32 + tx] + Ps[(1 * 8 + ty) * 32 + tx] +
            Ps[(2 * 8 + ty) * 32 + tx] + Ps[(3 * 8 + ty) * 32 + tx];

  const int gb = b0 + ty;
  const int gn = n0 + tx;
  const size_t oidx = ((size_t)gb * SEQ + t) * HSZ + gn;
  const float v = tanhf(s + out[oidx]);
  out[oidx] = v;
  hn[(size_t)gb * HSZ + gn] = v;
}

// ---------------------------------------------------------------------------
extern "C" void kernel_launch(void* const* d_in, const int* in_sizes, int n_in,
                              void* d_out, int out_size, void* d_ws, size_t ws_size,
                              hipStream_t stream) {
  const float* inputs = (const float*)d_in[0];  // (64, 512, 512)
  const float* h_prev = (const float*)d_in[1];  // (64, 1024)
  const float* W_xh   = (const float*)d_in[2];  // (512, 1024)
  const float* W_hh   = (const float*)d_in[3];  // (1024, 1024)
  const float* b_h    = (const float*)d_in[4];  // (1024,)
  float* out = (float*)d_out;                   // (64, 512, 1024)

  float* h_a = (float*)d_ws;                    // 64*1024 floats
  float* h_b = h_a + BATCH * HSZ;               // 64*1024 floats

  // 1. x_proj -> d_out (in-place with the recurrence)
  dim3 g1(HSZ / 64, (BATCH * SEQ) / 64);        // (16, 512)
  xproj_gemm<<<g1, 256, 0, stream>>>(inputs, W_xh, b_h, out);

  // 2. h0 = h_prev
  copy_h<<<256, 256, 0, stream>>>(h_prev, h_a);

  // 3. 512 sequential timesteps
  float* src = h_a;
  float* dst = h_b;
  for (int t = 0; t < SEQ; ++t) {
    rnn_step<<<dim3(HSZ / 32, BATCH / 8), 256, 0, stream>>>(src, W_hh, out, dst, t);
    float* tmp = src; src = dst; dst = tmp;
  }
}

// Round 2
// 4487.461 us; speedup vs baseline: 1.4239x; 1.4239x over previous
//
#include <hip/hip_runtime.h>
#include <hip/hip_bf16.h>
#include <cmath>

#define BATCH 64
#define SEQ   512
#define ISZ   512
#define HSZ   1024

// Persistent-kernel partition: 64 WGs = 4 batch-groups x 16 col-groups.
#define NWG 64
#define BT  16   // batches per WG (one 16-row MFMA m-tile)
#define NT  64   // columns per WG (four 16-col MFMA n-tiles)

typedef __attribute__((ext_vector_type(8))) short short8;   // 8 bf16 (A/B frag)
typedef __attribute__((ext_vector_type(4))) float floatx4;  // C/D frag

__device__ __forceinline__ ushort f2bf(float f) {
  // round-to-nearest-even fp32 -> bf16
  unsigned u = __builtin_bit_cast(unsigned, f);
  unsigned r = (u + 0x7fffu + ((u >> 16) & 1u)) >> 16;
  return (ushort)r;
}

// ---------------------------------------------------------------------------
// Kernel 1: x_proj = inputs @ W_xh + b_h  (fp32 tiled GEMM -> d_out, in-place
// with the recurrence: step t reads xp[b,t,:] then overwrites it with h_t)
// ---------------------------------------------------------------------------
__global__ __launch_bounds__(256) void xproj_gemm(
    const float* __restrict__ A,     // (32768, 512)
    const float* __restrict__ Bw,    // (512, 1024)
    const float* __restrict__ bias,  // (1024,)
    float* __restrict__ C) {         // (32768, 1024)
  __shared__ float As[32 * 68];
  __shared__ float Bs[32 * 64];

  const int tid = threadIdx.x;
  const int n0 = blockIdx.x * 64;
  const int m0 = blockIdx.y * 64;
  const int ty = tid >> 4;
  const int tx = tid & 15;

  float acc[4][4] = {};

  for (int kt = 0; kt < ISZ; kt += 32) {
#pragma unroll
    for (int i = 0; i < 8; ++i) {
      int idx = tid + i * 256;
      int m = idx >> 5, k = idx & 31;
      As[k * 68 + m] = A[(size_t)(m0 + m) * ISZ + kt + k];
    }
#pragma unroll
    for (int i = 0; i < 8; ++i) {
      int idx = tid + i * 256;
      int k = idx >> 6, n = idx & 63;
      Bs[k * 64 + n] = Bw[(size_t)(kt + k) * HSZ + n0 + n];
    }
    __syncthreads();

#pragma unroll
    for (int k = 0; k < 32; ++k) {
      const float4 a4 = *(const float4*)(&As[k * 68 + ty * 4]);
      const float4 b4 = *(const float4*)(&Bs[k * 64 + tx * 4]);
      acc[0][0] = fmaf(a4.x, b4.x, acc[0][0]);
      acc[0][1] = fmaf(a4.x, b4.y, acc[0][1]);
      acc[0][2] = fmaf(a4.x, b4.z, acc[0][2]);
      acc[0][3] = fmaf(a4.x, b4.w, acc[0][3]);
      acc[1][0] = fmaf(a4.y, b4.x, acc[1][0]);
      acc[1][1] = fmaf(a4.y, b4.y, acc[1][1]);
      acc[1][2] = fmaf(a4.y, b4.z, acc[1][2]);
      acc[1][3] = fmaf(a4.y, b4.w, acc[1][3]);
      acc[2][0] = fmaf(a4.z, b4.x, acc[2][0]);
      acc[2][1] = fmaf(a4.z, b4.y, acc[2][1]);
      acc[2][2] = fmaf(a4.z, b4.z, acc[2][2]);
      acc[2][3] = fmaf(a4.z, b4.w, acc[2][3]);
      acc[3][0] = fmaf(a4.w, b4.x, acc[3][0]);
      acc[3][1] = fmaf(a4.w, b4.y, acc[3][1]);
      acc[3][2] = fmaf(a4.w, b4.z, acc[3][2]);
      acc[3][3] = fmaf(a4.w, b4.w, acc[3][3]);
    }
    __syncthreads();
  }

  const float4 bv = *(const float4*)(&bias[n0 + tx * 4]);
#pragma unroll
  for (int r = 0; r < 4; ++r) {
    float4 o;
    o.x = acc[r][0] + bv.x;
    o.y = acc[r][1] + bv.y;
    o.z = acc[r][2] + bv.z;
    o.w = acc[r][3] + bv.w;
    *(float4*)(&C[(size_t)(m0 + ty * 4 + r) * HSZ + n0 + tx * 4]) = o;
  }
}

// ---------------------------------------------------------------------------
// Kernel 2: zero the grid-barrier counter (d_ws is poisoned every call)
// ---------------------------------------------------------------------------
__global__ void init_cnt(int* c) {
  if (threadIdx.x == 0 && blockIdx.x == 0) *c = 0;
}

// ---------------------------------------------------------------------------
// Kernel 3: persistent RNN recurrence. 64 WGs x 256 threads, all co-resident
// (145 KB LDS -> 1 WG/CU, 64 of 256 CUs; dispatcher places all immediately).
// Per WG: W_hh[:, n0:n0+64] as bf16 MFMA B-fragments in LDS (loaded once).
// Per step: h (bf16, global ping-pong) -> A-frags; 32 MFMAs (4 waves K-split);
// LDS reduce; tanh(+xp from d_out); write out fp32 + h_next bf16; grid barrier.
// ---------------------------------------------------------------------------
__global__ __launch_bounds__(256, 1) void rnn_persistent(
    const float* __restrict__ h_prev,   // (64, 1024) fp32
    const float* __restrict__ W,        // (1024, 1024) fp32
    float* __restrict__ out,            // (64, 512, 1024) fp32 (xp in, h out)
    ushort* __restrict__ h_a,           // (64, 1024) bf16 ping
    ushort* __restrict__ h_b,           // (64, 1024) bf16 pong
    int* __restrict__ cnt) {            // grid barrier counter (zeroed)
  extern __shared__ char smem[];
  ushort* Wfrag = (ushort*)smem;                 // 32kc*4nt*64lane*8 = 128 KB
  float*  Cred  = (float*)(smem + 131072);       // 4 waves * 16 * 68 floats

  const int tid = threadIdx.x;
  const int gb = blockIdx.x & 3;       // batch group 0..3
  const int gn = blockIdx.x >> 2;      // col group 0..15
  const int b0 = gb * BT;
  const int n0 = gn * NT;

  // ---- one-time: W_hh column slice -> bf16 fragments in LDS ----
  for (int it = tid; it < 1024 * 16; it += 256) {  // 16 float4 per k-row
    int k  = it >> 4;
    int c4 = (it & 15) << 2;
    float4 w4 = *(const float4*)&W[(size_t)k * HSZ + n0 + c4];
    int kc = k >> 5, j = k & 7, q = (k >> 3) & 3;
    float wv[4] = {w4.x, w4.y, w4.z, w4.w};
#pragma unroll
    for (int e = 0; e < 4; ++e) {
      int n = c4 + e;
      int nt = n >> 4;
      int lane = q * 16 + (n & 15);
      Wfrag[((kc * 4 + nt) * 64 + lane) * 8 + j] = f2bf(wv[e]);
    }
  }

  // ---- one-time: h0 = bf16(h_prev), written by the 4 gn==0 WGs ----
  if (gn == 0) {
    for (int it = tid; it < BT * (HSZ / 4); it += 256) {
      int r = it >> 8;            // 256 float4 per row
      int c = (it & 255) << 2;
      float4 v = *(const float4*)&h_prev[(size_t)(b0 + r) * HSZ + c];
      ushort4 o;
      o.x = f2bf(v.x); o.y = f2bf(v.y); o.z = f2bf(v.z); o.w = f2bf(v.w);
      *(ushort4*)&h_a[(size_t)(b0 + r) * HSZ + c] = o;
    }
  }

  int target = NWG;
  // ---- grid barrier (release-fence + monotonic count + acquire-fence) ----
#define GRID_BARRIER()                                                        \
  do {                                                                        \
    __syncthreads();                                                          \
    if (tid == 0) {                                                           \
      __threadfence();                                                        \
      atomicAdd(cnt, 1);                                                      \
      while (__hip_atomic_load(cnt, __ATOMIC_RELAXED,                         \
                               __HIP_MEMORY_SCOPE_AGENT) < target)            \
        __builtin_amdgcn_s_sleep(1);                                          \
      __threadfence();                                                        \
    }                                                                         \
    __syncthreads();                                                          \
    target += NWG;                                                            \
  } while (0)

  GRID_BARRIER();   // h0 + (implicitly) everyone's Wfrag ready

  const int w  = tid >> 6;             // wave 0..3 -> K quarter
  const int l  = tid & 63;
  const int bRow = b0 + (l & 15);      // A-frag row (batch)
  const int kq = ((l >> 4) & 3) * 8;   // A/B frag k sub-offset

  ushort* hc = h_a;
  ushort* hn = h_b;

  for (int t = 0; t < SEQ; ++t) {
    floatx4 acc[4] = {floatx4{0.f, 0.f, 0.f, 0.f}, floatx4{0.f, 0.f, 0.f, 0.f},
                      floatx4{0.f, 0.f, 0.f, 0.f}, floatx4{0.f, 0.f, 0.f, 0.f}};
    const ushort* hrow = hc + (size_t)bRow * HSZ;
#pragma unroll
    for (int i = 0; i < 8; ++i) {
      const int kc = w * 8 + i;
      short8 a8 = *(const short8*)(hrow + kc * 32 + kq);
#pragma unroll
      for (int nt = 0; nt < 4; ++nt) {
        short8 b8 = *(const short8*)&Wfrag[((kc * 4 + nt) * 64 + l) * 8];
        acc[nt] = __builtin_amdgcn_mfma_f32_16x16x32_bf16(a8, b8, acc[nt], 0, 0, 0);
      }
    }

    // partial C tiles -> LDS (C/D layout: col=lane&15, row=(lane>>4)*4+reg)
    {
      const int rbase = (l >> 4) * 4;
      const int cbase = l & 15;
#pragma unroll
      for (int nt = 0; nt < 4; ++nt)
#pragma unroll
        for (int r = 0; r < 4; ++r)
          Cred[(w * 16 + rbase + r) * 68 + nt * 16 + cbase] = acc[nt][r];
    }
    __syncthreads();

    // reduce 4 wave partials + epilogue: tanh(s + xp) -> out fp32, h_next bf16
    {
      const int b  = tid >> 4;
      const int n4 = (tid & 15) << 2;
      float4 v0 = *(const float4*)&Cred[(0 * 16 + b) * 68 + n4];
      float4 v1 = *(const float4*)&Cred[(1 * 16 + b) * 68 + n4];
      float4 v2 = *(const float4*)&Cred[(2 * 16 + b) * 68 + n4];
      float4 v3 = *(const float4*)&Cred[(3 * 16 + b) * 68 + n4];
      float4 s;
      s.x = v0.x + v1.x + v2.x + v3.x;
      s.y = v0.y + v1.y + v2.y + v3.y;
      s.z = v0.z + v1.z + v2.z + v3.z;
      s.w = v0.w + v1.w + v2.w + v3.w;
      const size_t oidx = ((size_t)(b0 + b) * SEQ + t) * HSZ + n0 + n4;
      float4 xp = *(const float4*)&out[oidx];
      float4 hv;
      hv.x = tanhf(s.x + xp.x);
      hv.y = tanhf(s.y + xp.y);
      hv.z = tanhf(s.z + xp.z);
      hv.w = tanhf(s.w + xp.w);
      *(float4*)&out[oidx] = hv;
      ushort4 hb;
      hb.x = f2bf(hv.x); hb.y = f2bf(hv.y); hb.z = f2bf(hv.z); hb.w = f2bf(hv.w);
      *(ushort4*)&hn[(size_t)(b0 + b) * HSZ + n0 + n4] = hb;
    }

    GRID_BARRIER();

    ushort* tmp = hc; hc = hn; hn = tmp;
  }
#undef GRID_BARRIER
}

// ---------------------------------------------------------------------------
extern "C" void kernel_launch(void* const* d_in, const int* in_sizes, int n_in,
                              void* d_out, int out_size, void* d_ws, size_t ws_size,
                              hipStream_t stream) {
  const float* inputs = (const float*)d_in[0];  // (64, 512, 512)
  const float* h_prev = (const float*)d_in[1];  // (64, 1024)
  const float* W_xh   = (const float*)d_in[2];  // (512, 1024)
  const float* W_hh   = (const float*)d_in[3];  // (1024, 1024)
  const float* b_h    = (const float*)d_in[4];  // (1024,)
  float* out = (float*)d_out;                   // (64, 512, 1024)

  int*    cnt = (int*)d_ws;
  ushort* h_a = (ushort*)((char*)d_ws + 256);
  ushort* h_b = h_a + BATCH * HSZ;              // 128 KB each

  // 1. x_proj -> d_out
  dim3 g1(HSZ / 64, (BATCH * SEQ) / 64);        // (16, 512)
  xproj_gemm<<<g1, 256, 0, stream>>>(inputs, W_xh, b_h, out);

  // 2. zero barrier counter (ws is re-poisoned before every call)
  init_cnt<<<1, 64, 0, stream>>>(cnt);

  // 3. persistent recurrence (needs 145 KB dynamic LDS)
  const int smem_bytes = 131072 + 4 * 16 * 68 * (int)sizeof(float);  // 148480
  hipFuncSetAttribute((const void*)rnn_persistent,
                      hipFuncAttributeMaxDynamicSharedMemorySize, smem_bytes);
  rnn_persistent<<<NWG, 256, smem_bytes, stream>>>(h_prev, W_hh, out, h_a, h_b, cnt);
}

// Round 3
// 2340.437 us; speedup vs baseline: 2.7301x; 1.9174x over previous
//
#include <hip/hip_runtime.h>
#include <hip/hip_bf16.h>
#include <cmath>

#define BATCH 64
#define SEQ   512
#define ISZ   512
#define HSZ   1024

// Persistent-kernel partition: 64 WGs = 4 batch-groups x 16 col-groups.
// Batch groups are fully independent (h_next[b,:] depends only on h[b,:]),
// so each batch group syncs with its OWN 16-WG barrier.
#define NWG 64
#define BT  16   // batches per WG (one 16-row MFMA m-tile)
#define NT  64   // columns per WG (four 16-col MFMA n-tiles)
#define GRP_WGS 16

typedef __attribute__((ext_vector_type(8))) short short8;   // 8 bf16 (A/B frag)
typedef __attribute__((ext_vector_type(4))) float floatx4;  // C/D frag
typedef unsigned long long ull;

union Frag { short8 s8; ull u2[2]; };

__device__ __forceinline__ ushort f2bf(float f) {
  unsigned u = __builtin_bit_cast(unsigned, f);
  unsigned r = (u + 0x7fffu + ((u >> 16) & 1u)) >> 16;
  return (ushort)r;
}
__device__ __forceinline__ ull pack4(float a, float b, float c, float d) {
  unsigned lo = (unsigned)f2bf(a) | ((unsigned)f2bf(b) << 16);
  unsigned hi = (unsigned)f2bf(c) | ((unsigned)f2bf(d) << 16);
  return (ull)lo | ((ull)hi << 32);
}

// ---------------------------------------------------------------------------
// Kernel 1: x_proj = inputs @ W_xh + b_h  (fp32 tiled GEMM -> d_out, in-place
// with the recurrence: step t reads xp[b,t,:] then overwrites it with h_t)
// ---------------------------------------------------------------------------
__global__ __launch_bounds__(256) void xproj_gemm(
    const float* __restrict__ A,     // (32768, 512)
    const float* __restrict__ Bw,    // (512, 1024)
    const float* __restrict__ bias,  // (1024,)
    float* __restrict__ C) {         // (32768, 1024)
  __shared__ float As[32 * 68];
  __shared__ float Bs[32 * 64];

  const int tid = threadIdx.x;
  const int n0 = blockIdx.x * 64;
  const int m0 = blockIdx.y * 64;
  const int ty = tid >> 4;
  const int tx = tid & 15;

  float acc[4][4] = {};

  for (int kt = 0; kt < ISZ; kt += 32) {
#pragma unroll
    for (int i = 0; i < 8; ++i) {
      int idx = tid + i * 256;
      int m = idx >> 5, k = idx & 31;
      As[k * 68 + m] = A[(size_t)(m0 + m) * ISZ + kt + k];
    }
#pragma unroll
    for (int i = 0; i < 8; ++i) {
      int idx = tid + i * 256;
      int k = idx >> 6, n = idx & 63;
      Bs[k * 64 + n] = Bw[(size_t)(kt + k) * HSZ + n0 + n];
    }
    __syncthreads();

#pragma unroll
    for (int k = 0; k < 32; ++k) {
      const float4 a4 = *(const float4*)(&As[k * 68 + ty * 4]);
      const float4 b4 = *(const float4*)(&Bs[k * 64 + tx * 4]);
      acc[0][0] = fmaf(a4.x, b4.x, acc[0][0]);
      acc[0][1] = fmaf(a4.x, b4.y, acc[0][1]);
      acc[0][2] = fmaf(a4.x, b4.z, acc[0][2]);
      acc[0][3] = fmaf(a4.x, b4.w, acc[0][3]);
      acc[1][0] = fmaf(a4.y, b4.x, acc[1][0]);
      acc[1][1] = fmaf(a4.y, b4.y, acc[1][1]);
      acc[1][2] = fmaf(a4.y, b4.z, acc[1][2]);
      acc[1][3] = fmaf(a4.y, b4.w, acc[1][3]);
      acc[2][0] = fmaf(a4.z, b4.x, acc[2][0]);
      acc[2][1] = fmaf(a4.z, b4.y, acc[2][1]);
      acc[2][2] = fmaf(a4.z, b4.z, acc[2][2]);
      acc[2][3] = fmaf(a4.z, b4.w, acc[2][3]);
      acc[3][0] = fmaf(a4.w, b4.x, acc[3][0]);
      acc[3][1] = fmaf(a4.w, b4.y, acc[3][1]);
      acc[3][2] = fmaf(a4.w, b4.z, acc[3][2]);
      acc[3][3] = fmaf(a4.w, b4.w, acc[3][3]);
    }
    __syncthreads();
  }

  const float4 bv = *(const float4*)(&bias[n0 + tx * 4]);
#pragma unroll
  for (int r = 0; r < 4; ++r) {
    float4 o;
    o.x = acc[r][0] + bv.x;
    o.y = acc[r][1] + bv.y;
    o.z = acc[r][2] + bv.z;
    o.w = acc[r][3] + bv.w;
    *(float4*)(&C[(size_t)(m0 + ty * 4 + r) * HSZ + n0 + tx * 4]) = o;
  }
}

// ---------------------------------------------------------------------------
// Kernel 2: zero the 4 per-group barrier counters (ws is re-poisoned per call)
// ---------------------------------------------------------------------------
__global__ void init_cnt(int* c) { c[threadIdx.x] = 0; }

// ---------------------------------------------------------------------------
// Kernel 3: persistent RNN recurrence. 64 WGs x 256 thr, 1 WG/CU (145 KB LDS).
// All cross-WG traffic (h ping-pong, counters) via RELAXED agent-scope
// atomics (sc1, LLC-coherent) -> NO fences -> no buffer_wbl2/buffer_inv.
// __syncthreads()'s vmcnt(0) drain before the arrive-add = release ordering.
// ---------------------------------------------------------------------------
__global__ __launch_bounds__(256, 1) void rnn_persistent(
    const float* __restrict__ h_prev,   // (64, 1024) fp32
    const float* __restrict__ W,        // (1024, 1024) fp32
    float* __restrict__ out,            // (64, 512, 1024) fp32 (xp in, h out)
    ull* __restrict__ h_a,              // (64, 256) bf16x4 ping
    ull* __restrict__ h_b,              // (64, 256) bf16x4 pong
    int* __restrict__ cnt) {            // 4 barrier counters, 256B apart
  extern __shared__ char smem[];
  ushort* Wfrag = (ushort*)smem;                 // 32kc*4nt*64lane*8 = 128 KB
  float*  Cred  = (float*)(smem + 131072);       // 4 waves * 16 * 68 floats

  const int tid = threadIdx.x;
  const int gb = blockIdx.x & 3;       // batch group 0..3
  const int gn = blockIdx.x >> 2;      // col group 0..15
  const int b0 = gb * BT;
  const int n0 = gn * NT;
  int* cnt_g = cnt + gb * 64;          // per-group counter line

  // ---- one-time: W_hh column slice -> bf16 fragments in LDS ----
  for (int it = tid; it < 1024 * 16; it += 256) {
    int k  = it >> 4;
    int c4 = (it & 15) << 2;
    float4 w4 = *(const float4*)&W[(size_t)k * HSZ + n0 + c4];
    int kc = k >> 5, j = k & 7, q = (k >> 3) & 3;
    float wv[4] = {w4.x, w4.y, w4.z, w4.w};
#pragma unroll
    for (int e = 0; e < 4; ++e) {
      int n = c4 + e;
      int nt = n >> 4;
      int lane = q * 16 + (n & 15);
      Wfrag[((kc * 4 + nt) * 64 + lane) * 8 + j] = f2bf(wv[e]);
    }
  }

  // ---- one-time: h0 = bf16(h_prev), written by the 4 gn==0 WGs (sc1) ----
  if (gn == 0) {
    for (int it = tid; it < BT * 256; it += 256) {
      int r = it >> 8;
      int c4 = (it & 255) << 2;
      float4 v = *(const float4*)&h_prev[(size_t)(b0 + r) * HSZ + c4];
      __hip_atomic_store(&h_a[(size_t)(b0 + r) * 256 + (c4 >> 2)],
                         pack4(v.x, v.y, v.z, v.w),
                         __ATOMIC_RELAXED, __HIP_MEMORY_SCOPE_AGENT);
    }
  }

  int target = GRP_WGS;
#define GRID_BARRIER()                                                        \
  do {                                                                        \
    __syncthreads(); /* drains vmcnt(0): all sc1 h-stores globally visible */ \
    if (tid == 0) {                                                           \
      __hip_atomic_fetch_add(cnt_g, 1, __ATOMIC_RELAXED,                      \
                             __HIP_MEMORY_SCOPE_AGENT);                       \
      while (__hip_atomic_load(cnt_g, __ATOMIC_RELAXED,                       \
                               __HIP_MEMORY_SCOPE_AGENT) < target)            \
        __builtin_amdgcn_s_sleep(1);                                          \
    }                                                                         \
    __syncthreads();                                                          \
    target += GRP_WGS;                                                        \
  } while (0)

  const int w  = tid >> 6;             // wave 0..3 -> K quarter
  const int l  = tid & 63;
  const int bRow = b0 + (l & 15);      // A-frag row (batch)
  const int q2 = ((l >> 4) & 3) * 2;   // frag k sub-offset in 8B units

  // epilogue mapping (also used for xp prefetch)
  const int eb  = tid >> 4;            // 0..15 batch row
  const int en4 = (tid & 15) << 2;     // col*4
  const size_t obase = ((size_t)(b0 + eb) * SEQ) * HSZ + n0 + en4;

  ull* hc = h_a;
  ull* hn = h_b;

  // prefetch xp for t=0 (no dependency on h)
  float4 xp = *(const float4*)&out[obase];

  GRID_BARRIER();   // h0 ready

  for (int t = 0; t < SEQ; ++t) {
    // ---- load this wave's 8 A-frags (sc1, pipelined 8B loads) ----
    Frag af[8];
    const ull* hq = hc + (size_t)bRow * 256;
#pragma unroll
    for (int i = 0; i < 8; ++i) {
      const int off = (w * 8 + i) * 8 + q2;
      af[i].u2[0] = __hip_atomic_load(hq + off, __ATOMIC_RELAXED,
                                      __HIP_MEMORY_SCOPE_AGENT);
      af[i].u2[1] = __hip_atomic_load(hq + off + 1, __ATOMIC_RELAXED,
                                      __HIP_MEMORY_SCOPE_AGENT);
    }

    floatx4 acc[4] = {floatx4{0.f, 0.f, 0.f, 0.f}, floatx4{0.f, 0.f, 0.f, 0.f},
                      floatx4{0.f, 0.f, 0.f, 0.f}, floatx4{0.f, 0.f, 0.f, 0.f}};
#pragma unroll
    for (int i = 0; i < 8; ++i) {
      const int kc = w * 8 + i;
#pragma unroll
      for (int nt = 0; nt < 4; ++nt) {
        short8 b8 = *(const short8*)&Wfrag[((kc * 4 + nt) * 64 + l) * 8];
        acc[nt] = __builtin_amdgcn_mfma_f32_16x16x32_bf16(af[i].s8, b8, acc[nt], 0, 0, 0);
      }
    }

    // partial C tiles -> LDS (C/D layout: col=lane&15, row=(lane>>4)*4+reg)
    {
      const int rbase = (l >> 4) * 4;
      const int cbase = l & 15;
#pragma unroll
      for (int nt = 0; nt < 4; ++nt)
#pragma unroll
        for (int r = 0; r < 4; ++r)
          Cred[(w * 16 + rbase + r) * 68 + nt * 16 + cbase] = acc[nt][r];
    }
    __syncthreads();

    // reduce 4 wave partials + epilogue
    {
      float4 v0 = *(const float4*)&Cred[(0 * 16 + eb) * 68 + en4];
      float4 v1 = *(const float4*)&Cred[(1 * 16 + eb) * 68 + en4];
      float4 v2 = *(const float4*)&Cred[(2 * 16 + eb) * 68 + en4];
      float4 v3 = *(const float4*)&Cred[(3 * 16 + eb) * 68 + en4];
      float4 hv;
      hv.x = tanhf(v0.x + v1.x + v2.x + v3.x + xp.x);
      hv.y = tanhf(v0.y + v1.y + v2.y + v3.y + xp.y);
      hv.z = tanhf(v0.z + v1.z + v2.z + v3.z + xp.z);
      hv.w = tanhf(v0.w + v1.w + v2.w + v3.w + xp.w);
      *(float4*)&out[obase + (size_t)t * HSZ] = hv;   // WG-private: normal store
      __hip_atomic_store(&hn[((size_t)(b0 + eb) * 256) + ((n0 + en4) >> 2)],
                         pack4(hv.x, hv.y, hv.z, hv.w),
                         __ATOMIC_RELAXED, __HIP_MEMORY_SCOPE_AGENT);
      // prefetch next xp while peers finish (hidden under barrier wait)
      if (t + 1 < SEQ) xp = *(const float4*)&out[obase + (size_t)(t + 1) * HSZ];
    }

    GRID_BARRIER();

    ull* tmp = hc; hc = hn; hn = tmp;
  }
#undef GRID_BARRIER
}

// ---------------------------------------------------------------------------
extern "C" void kernel_launch(void* const* d_in, const int* in_sizes, int n_in,
                              void* d_out, int out_size, void* d_ws, size_t ws_size,
                              hipStream_t stream) {
  const float* inputs = (const float*)d_in[0];  // (64, 512, 512)
  const float* h_prev = (const float*)d_in[1];  // (64, 1024)
  const float* W_xh   = (const float*)d_in[2];  // (512, 1024)
  const float* W_hh   = (const float*)d_in[3];  // (1024, 1024)
  const float* b_h    = (const float*)d_in[4];  // (1024,)
  float* out = (float*)d_out;                   // (64, 512, 1024)

  int* cnt = (int*)d_ws;                        // 4 counters, 256B apart
  ull* h_a = (ull*)((char*)d_ws + 1024);
  ull* h_b = h_a + BATCH * 256;                 // 128 KB each

  // 1. x_proj -> d_out
  dim3 g1(HSZ / 64, (BATCH * SEQ) / 64);        // (16, 512)
  xproj_gemm<<<g1, 256, 0, stream>>>(inputs, W_xh, b_h, out);

  // 2. zero barrier counters
  init_cnt<<<1, 256, 0, stream>>>(cnt);

  // 3. persistent recurrence (145 KB dynamic LDS -> 1 WG/CU)
  const int smem_bytes = 131072 + 4 * 16 * 68 * (int)sizeof(float);  // 148480
  hipFuncSetAttribute((const void*)rnn_persistent,
                      hipFuncAttributeMaxDynamicSharedMemorySize, smem_bytes);
  rnn_persistent<<<NWG, 256, smem_bytes, stream>>>(h_prev, W_hh, out, h_a, h_b, cnt);
}